// Round 14
// baseline (148.022 us; speedup 1.0000x reference)
//
#include <hip/hip_runtime.h>
#include <hip/hip_bf16.h>

// Problem constants
#define HEADS   16
#define HD      64
#define DMODEL  1024
#define LQ      2048
#define LK      2048
#define BATCH   4
#define MROWS   8192  // BATCH*LQ

typedef __attribute__((ext_vector_type(8))) short short8;   // 8 bf16 = 4 VGPR
typedef __attribute__((ext_vector_type(4))) float f32x4;    // MFMA 16x16 acc
typedef __attribute__((ext_vector_type(16))) float f32x16;  // MFMA 32x32 acc
typedef __attribute__((ext_vector_type(2))) unsigned int uint2v;
typedef __attribute__((ext_vector_type(2))) short bf16x2;

union V4u { unsigned u[4]; short8 s8; };

static __device__ __forceinline__ unsigned short f2bf(float f) {
  unsigned u = __builtin_bit_cast(unsigned, f);
  u = (u + 0x7FFFu + ((u >> 16) & 1u)) >> 16;  // RNE
  return (unsigned short)u;
}

static __device__ __forceinline__ unsigned cvtpk(float lo, float hi) {
  unsigned w;
  asm("v_cvt_pk_bf16_f32 %0, %1, %2" : "=v"(w) : "v"(lo), "v"(hi));
  return w;  // {lo16: bf16(lo), hi16: bf16(hi)}
}

// v_permlane32_swap_b32 vdst, vsrc: swaps vdst's UPPER 32 lanes with vsrc's
// LOWER 32 lanes (verified round 4).
static __device__ __forceinline__ void permswap(unsigned &a, unsigned &b) {
  asm volatile("v_permlane32_swap_b32 %0, %1" : "+v"(a), "+v"(b));
}

static __device__ __forceinline__ void gload_lds16(const void* g, void* l) {
  __builtin_amdgcn_global_load_lds(
      (const __attribute__((address_space(1))) unsigned int*)g,
      (__attribute__((address_space(3))) unsigned int*)l, 16, 0, 0);
}

static __device__ __forceinline__ unsigned lds_addr(const void* p) {
  return (unsigned)(size_t)(const __attribute__((address_space(3))) void*)p;
}

static __device__ __forceinline__ void ds_read128o(unsigned addr, int imm, V4u &d) {
  asm volatile("ds_read_b128 %0, %1 offset:%c2" : "=v"(d.s8) : "v"(addr), "i"(imm));
}

static __device__ __forceinline__ void ds_read_tro(unsigned addr, int imm, uint2v &d) {
  asm volatile("ds_read_b64_tr_b16 %0, %1 offset:%c2" : "=v"(d) : "v"(addr), "i"(imm));
}

// s2 += dot2(w, w), z += dot2(w, {1,1}) using bf16 dot if available.
#if __has_builtin(__builtin_amdgcn_fdot2_f32_bf16)
#define HAVE_BF16_DOT2 1
static __device__ __forceinline__ float dot2_sq(unsigned w, float acc) {
  bf16x2 v = __builtin_bit_cast(bf16x2, w);
  return __builtin_amdgcn_fdot2_f32_bf16(v, v, acc, false);
}
static __device__ __forceinline__ float dot2_sum(unsigned w, float acc) {
  bf16x2 ones = __builtin_bit_cast(bf16x2, 0x3F803F80u);  // {1.0bf, 1.0bf}
  bf16x2 v = __builtin_bit_cast(bf16x2, w);
  return __builtin_amdgcn_fdot2_f32_bf16(v, ones, acc, false);
}
#else
#define HAVE_BF16_DOT2 0
#endif

// ---------------- fp32 -> bf16 convert, single flat launch ----------------
// Flat float4-range: [0,N4I): inp1, [N4I,2*N4I): inp2, then Wq (scaled), Wk, Wv.
#define N4I 2097152   // 8192*1024/4
#define N4W 262144    // 1024*1024/4
__global__ void cvt_all_kernel(const float* __restrict__ i1, unsigned short* __restrict__ o1,
                               const float* __restrict__ i2, unsigned short* __restrict__ o2,
                               const float* __restrict__ wq, unsigned short* __restrict__ oq,
                               const float* __restrict__ wk, unsigned short* __restrict__ ok,
                               const float* __restrict__ wv, unsigned short* __restrict__ ov,
                               float scaleq) {
  int i = blockIdx.x * blockDim.x + threadIdx.x;
  const float* s;
  unsigned short* d;
  int off;
  float sc = 1.0f;
  if (i < 2 * N4I) {
    if (i < N4I) { s = i1; d = o1; off = i; }
    else { s = i2; d = o2; off = i - N4I; }
  } else {
    int j = i - 2 * N4I;
    if (j < N4W) { s = wq; d = oq; off = j; sc = scaleq; }
    else if (j < 2 * N4W) { s = wk; d = ok; off = j - N4W; }
    else { s = wv; d = ov; off = j - 2 * N4W; }
  }
  float4 v = ((const float4*)s)[off];
  ushort4 o;
  o.x = f2bf(v.x * sc); o.y = f2bf(v.y * sc); o.z = f2bf(v.z * sc); o.w = f2bf(v.w * sc);
  ((ushort4*)d)[off] = o;
}

// ---------------- fused QKV GEMM: z selects (A,W,bias,C,bscale) ----------------
// BK=64 (r13 proven): 16 K-steps, 2 barriers each. 128x128 tile, 4 waves,
// 32 KB LDS -> 4 blocks/CU. 8-slot rows with XOR (sl ^ (r&7)) swizzle.
__global__ __launch_bounds__(256, 4) void gemm3_kernel(
    const unsigned short* __restrict__ X1,
    const unsigned short* __restrict__ X2,
    const unsigned short* __restrict__ Wqb,
    const unsigned short* __restrict__ Wkb,
    const unsigned short* __restrict__ Wvb,
    const float* __restrict__ bq,
    const float* __restrict__ bk,
    const float* __restrict__ bv,
    unsigned short* __restrict__ Qb,
    unsigned short* __restrict__ Kb,
    unsigned short* __restrict__ Vb,
    float cexp) {
  __shared__ __attribute__((aligned(16))) unsigned short As[128 * 64];
  __shared__ __attribute__((aligned(16))) unsigned short Bs[128 * 64];
  const int sel = blockIdx.z;
  const unsigned short* A = (sel == 0) ? X1 : X2;
  const unsigned short* W = (sel == 0) ? Wqb : (sel == 1) ? Wkb : Wvb;
  const float* bias = (sel == 0) ? bq : (sel == 1) ? bk : bv;
  unsigned short* C = (sel == 0) ? Qb : (sel == 1) ? Kb : Vb;
  const float bscale = (sel == 0) ? cexp : 1.0f;

  const int tid = threadIdx.x;
  const int l = tid & 63, w = tid >> 6;
  const int c = l & 15, g = l >> 4;
  const int wm = w >> 1, wn = w & 1;
  const int m0 = blockIdx.x * 128, n0 = blockIdx.y * 128;

  f32x4 acc[4][4];
#pragma unroll
  for (int i = 0; i < 4; ++i)
#pragma unroll
    for (int j = 0; j < 4; ++j) acc[i][j] = (f32x4){0.f, 0.f, 0.f, 0.f};

  for (int k0 = 0; k0 < 1024; k0 += 64) {
#pragma unroll
    for (int is = 0; is < 4; ++is) {
      int lin = is * 256 + tid;
      int r = lin >> 3, sl = lin & 7;
      int gofs = (sl ^ (r & 7)) * 8;
      gload_lds16(A + (size_t)(m0 + r) * 1024 + k0 + gofs,
                  &As[(is * 256 + (tid & ~63)) * 8]);
      gload_lds16(W + (size_t)(n0 + r) * 1024 + k0 + gofs,
                  &Bs[(is * 256 + (tid & ~63)) * 8]);
    }
    __syncthreads();
#pragma unroll
    for (int kk = 0; kk < 2; ++kk) {
      short8 af[4], bfr[4];
#pragma unroll
      for (int mt = 0; mt < 4; ++mt) {
        int row = wm * 64 + mt * 16 + c;
        int ch = kk * 4 + g;
        af[mt] = *(const short8*)((const char*)As + row * 128 + ((ch ^ (row & 7)) << 4));
      }
#pragma unroll
      for (int nt = 0; nt < 4; ++nt) {
        int row = wn * 64 + nt * 16 + c;
        int ch = kk * 4 + g;
        bfr[nt] = *(const short8*)((const char*)Bs + row * 128 + ((ch ^ (row & 7)) << 4));
      }
      __builtin_amdgcn_s_setprio(1);
#pragma unroll
      for (int mt = 0; mt < 4; ++mt)
#pragma unroll
        for (int nt = 0; nt < 4; ++nt)
          acc[mt][nt] = __builtin_amdgcn_mfma_f32_16x16x32_bf16(af[mt], bfr[nt], acc[mt][nt], 0, 0, 0);
      __builtin_amdgcn_s_setprio(0);
    }
    __syncthreads();
  }
  float bv4[4];
#pragma unroll
  for (int nt = 0; nt < 4; ++nt) bv4[nt] = bias[n0 + wn * 64 + nt * 16 + c] * bscale;
#pragma unroll
  for (int mt = 0; mt < 4; ++mt)
#pragma unroll
    for (int nt = 0; nt < 4; ++nt)
#pragma unroll
      for (int r = 0; r < 4; ++r) {
        int m = m0 + wm * 64 + mt * 16 + g * 4 + r;
        int n = n0 + wn * 64 + nt * 16 + c;
        C[(size_t)m * 1024 + n] = f2bf(acc[mt][nt][r] + bv4[nt]);
      }
}

// ---------------- fused attention, 8-wave 32x32 swapped-QK^T ----------------
// r9 per-subtile schedule (frozen) with KVBLK=128: 16 K-tiles instead of 32
// halves the vmcnt-drain + 8-wave barrier count (same mechanism as gemm BK=64).
// LDS 65 KB -> 2 blocks/CU (grid 512 = 2/CU anyway; TLP unchanged).
__global__ __launch_bounds__(512) void attn_kernel(
    const unsigned short* __restrict__ Q,
    const unsigned short* __restrict__ K,
    const unsigned short* __restrict__ V,
    float* __restrict__ out,
    const int* __restrict__ rescale_flag) {
  __shared__ __attribute__((aligned(16))) unsigned short Kbuf[2][128 * 64];
  __shared__ __attribute__((aligned(16))) unsigned short Vbuf[2][128 * 64];
  __shared__ float ivLds[8][32];

  const int tid = threadIdx.x;
  const int lane = tid & 63, w = tid >> 6;
  const int l31 = lane & 31, hi = lane >> 5;

  // XCD-locality remap: all 8 q-tiles of one (b,h) on one XCD (gid%8 = xcd).
  const int gid = blockIdx.x;
  const int xcd = gid & 7;
  const int o = gid >> 3;
  const int bh = xcd * 8 + (o >> 3);
  const int qb = o & 7;
  const int bb = bh >> 4, h = bh & 15;
  const size_t qrowb = (size_t)bb * LQ + qb * 256 + w * 32;

  const int rs = *rescale_flag;

  // Q fragments (B-operand of swapped QK^T): lane holds Q[q=l31][d=ks*16+hi*8+j]
  short8 qf[4];
#pragma unroll
  for (int ks = 0; ks < 4; ++ks)
    qf[ks] = *(const short8*)(Q + (qrowb + l31) * 1024 + h * 64 + ks * 16 + hi * 8);

  // Staging source offsets (per-lane). Each thread stages 2 K + 2 V slots per
  // buffer; second slot = +64 kv rows (slot index +512 -> row +64, XOR chunk
  // unchanged since S&7 and row&7 are invariant).
  const size_t kvbase = (size_t)bb * LK * 1024 + (size_t)h * 64;
  const int k_kv = w * 8 + (lane >> 3);
  const int k_sl = (lane & 7) ^ (lane >> 3);
  const unsigned short* ksrc0 = K + kvbase + (size_t)k_kv * 1024 + k_sl * 8;
  const int v_kv = (w & 3) * 16 + ((lane >> 4) & 1) * 8 + ((lane >> 5) & 1) * 4 + ((lane >> 1) & 3);
  const int v_d  = (w >> 2) * 32 + ((lane >> 3) & 1) * 16 + (lane & 1) * 8;
  const unsigned short* vsrc0 = V + kvbase + (size_t)v_kv * 1024 + v_d;

  // Per-lane K LDS read offsets (byte), constant across tiles/subtiles.
  unsigned koff[4];
#pragma unroll
  for (int ks = 0; ks < 4; ++ks)
    koff[ks] = (unsigned)(l31 * 128 + ((((ks << 1) | hi) ^ (l31 & 7)) << 4));
  const unsigned kbase0 = lds_addr(&Kbuf[0][0]);
  const unsigned vbase0 = lds_addr(&Vbuf[0][0]);

  f32x16 po[2];
  po[0] = {}; po[1] = {};
  float za0 = 0.f, za1 = 0.f, s20 = 0.f, s21 = 0.f;

#define STAGE_ATTN(buf, adv)                                            \
  {                                                                     \
    gload_lds16(ksrc0 + (adv), &Kbuf[buf][w * 512]);                    \
    gload_lds16(ksrc0 + (adv) + 65536, &Kbuf[buf][4096 + w * 512]);     \
    gload_lds16(vsrc0 + (adv), &Vbuf[buf][w * 512]);                    \
    gload_lds16(vsrc0 + (adv) + 65536, &Vbuf[buf][4096 + w * 512]);     \
  }

  STAGE_ATTN(0, 0);
  __syncthreads();

  int cur = 0;
  for (int t = 0; t < LK / 128; ++t) {
    if (t < LK / 128 - 1) {
      STAGE_ATTN(cur ^ 1, (size_t)(t + 1) * 131072);
    }
    unsigned kaddr[4];
#pragma unroll
    for (int ks = 0; ks < 4; ++ks) kaddr[ks] = kbase0 + (unsigned)(cur * 16384) + koff[ks];
    const unsigned vtr = vbase0 + (unsigned)(cur * 16384) + (unsigned)(lane * 8);

#pragma unroll
    for (int s = 0; s < 4; ++s) {
      // V byte offsets for the two 16-kv steps of this subtile:
      // kv4 = 2s, 2s+1; block = kv4>>2 (64-kv F-block at +8192B), within = kv4&3.
      const int k4a = 2 * s, k4b = 2 * s + 1;
      const int voa = ((k4a >> 2) * 8192) + ((k4a & 3) * 1024);
      const int vob = ((k4b >> 2) * 8192) + ((k4b & 3) * 1024);
      // ---- issue ALL LDS reads for this subtile (4 K-frags + 8 V tr-reads)
      V4u kfr[4];
#pragma unroll
      for (int ks = 0; ks < 4; ++ks) ds_read128o(kaddr[ks], s * 4096, kfr[ks]);
      uint2v ta0, ta1, ta2, ta3, tb0, tb1, tb2, tb3;
      ds_read_tro(vtr, voa, ta0);
      ds_read_tro(vtr, voa + 512, ta1);
      ds_read_tro(vtr, voa + 4096, ta2);
      ds_read_tro(vtr, voa + 4608, ta3);
      ds_read_tro(vtr, vob, tb0);
      ds_read_tro(vtr, vob + 512, tb1);
      ds_read_tro(vtr, vob + 4096, tb2);
      ds_read_tro(vtr, vob + 4608, tb3);
      asm volatile("s_waitcnt lgkmcnt(8)" ::: "memory");  // K-frags ready
      __builtin_amdgcn_sched_barrier(0);
      // ---- QK^T (swapped): ps = S^T[kv=crow(r,hi)+32s][q=l31]
      f32x16 ps = {};
      __builtin_amdgcn_s_setprio(1);
      ps = __builtin_amdgcn_mfma_f32_32x32x16_bf16(kfr[0].s8, qf[0], ps, 0, 0, 0);
      ps = __builtin_amdgcn_mfma_f32_32x32x16_bf16(kfr[1].s8, qf[1], ps, 0, 0, 0);
      ps = __builtin_amdgcn_mfma_f32_32x32x16_bf16(kfr[2].s8, qf[2], ps, 0, 0, 0);
      ps = __builtin_amdgcn_mfma_f32_32x32x16_bf16(kfr[3].s8, qf[3], ps, 0, 0, 0);
      __builtin_amdgcn_s_setprio(0);
      // ---- softmax piece: lane-local exp
      float p[16];
#pragma unroll
      for (int r = 0; r < 16; ++r) p[r] = __builtin_amdgcn_exp2f(ps[r]);
      // ---- pack P to bf16 words (cvt_pk); wlo[b]={kv 8b+4hi, +1}, whi[b]={+2,+3}
      unsigned wlo[4], whi[4];
#pragma unroll
      for (int b = 0; b < 4; ++b) {
        wlo[b] = cvtpk(p[4 * b + 0], p[4 * b + 1]);
        whi[b] = cvtpk(p[4 * b + 2], p[4 * b + 3]);
      }
      // ---- accumulate z or s2 from packed words (off the PV critical path)
#if HAVE_BF16_DOT2
      if (rs) {
#pragma unroll
        for (int b = 0; b < 4; ++b) {
          s20 = dot2_sq(wlo[b], s20);
          s21 = dot2_sq(whi[b], s21);
        }
      } else {
#pragma unroll
        for (int b = 0; b < 4; ++b) {
          za0 = dot2_sum(wlo[b], za0);
          za1 = dot2_sum(whi[b], za1);
        }
      }
#else
      if (rs) {
#pragma unroll
        for (int r = 0; r < 8; ++r) {
          s20 = fmaf(p[2 * r], p[2 * r], s20);
          s21 = fmaf(p[2 * r + 1], p[2 * r + 1], s21);
        }
      } else {
#pragma unroll
        for (int r = 0; r < 8; ++r) {
          za0 += p[2 * r];
          za1 += p[2 * r + 1];
        }
      }
#endif
      // ---- PV ks=0 (kv4 = 2s): first 4 tr-reads ready at lgkmcnt(4)
      {
        unsigned a0 = wlo[0], b0 = wlo[1], a1 = whi[0], b1 = whi[1];
        permswap(a0, b0);
        permswap(a1, b1);
        V4u pau; pau.u[0] = a0; pau.u[1] = a1; pau.u[2] = b0; pau.u[3] = b1;
        asm volatile("s_waitcnt lgkmcnt(4)" ::: "memory");
        __builtin_amdgcn_sched_barrier(0);
        V4u v0u, v1u;
        v0u.u[0] = ta0[0]; v0u.u[1] = ta0[1]; v0u.u[2] = ta1[0]; v0u.u[3] = ta1[1];
        v1u.u[0] = ta2[0]; v1u.u[1] = ta2[1]; v1u.u[2] = ta3[0]; v1u.u[3] = ta3[1];
        __builtin_amdgcn_s_setprio(1);
        po[0] = __builtin_amdgcn_mfma_f32_32x32x16_bf16(pau.s8, v0u.s8, po[0], 0, 0, 0);
        po[1] = __builtin_amdgcn_mfma_f32_32x32x16_bf16(pau.s8, v1u.s8, po[1], 0, 0, 0);
        __builtin_amdgcn_s_setprio(0);
      }
      // ---- PV ks=1 (kv4 = 2s+1): remaining tr-reads at lgkmcnt(0)
      {
        unsigned a0 = wlo[2], b0 = wlo[3], a1 = whi[2], b1 = whi[3];
        permswap(a0, b0);
        permswap(a1, b1);
        V4u pau; pau.u[0] = a0; pau.u[1] = a1; pau.u[2] = b0; pau.u[3] = b1;
        asm volatile("s_waitcnt lgkmcnt(0)" ::: "memory");
        __builtin_amdgcn_sched_barrier(0);
        V4u v0u, v1u;
        v0u.u[0] = tb0[0]; v0u.u[1] = tb0[1]; v0u.u[2] = tb1[0]; v0u.u[3] = tb1[1];
        v1u.u[0] = tb2[0]; v1u.u[1] = tb2[1]; v1u.u[2] = tb3[0]; v1u.u[3] = tb3[1];
        __builtin_amdgcn_s_setprio(1);
        po[0] = __builtin_amdgcn_mfma_f32_32x32x16_bf16(pau.s8, v0u.s8, po[0], 0, 0, 0);
        po[1] = __builtin_amdgcn_mfma_f32_32x32x16_bf16(pau.s8, v1u.s8, po[1], 0, 0, 0);
        __builtin_amdgcn_s_setprio(0);
      }
    }
    __syncthreads();
    cur ^= 1;
  }

  // ---- denominators: combine accumulators, then the two kv-halves
  float zacc = za0 + za1;
  float s2acc = s20 + s21;
  float z2 = zacc + __shfl_xor(zacc, 32, 64);
  float s22 = s2acc + __shfl_xor(s2acc, 32, 64);
  float iv = rs ? (1.0f / sqrtf(s22)) : (1.0f / z2);
  ivLds[w][l31] = iv;  // both halves write identical value

  // ---- store: O[q=qrowb+crow(r,hi)][d=h*64+dt*32+l31] * iv[q]
#pragma unroll
  for (int dt = 0; dt < 2; ++dt)
#pragma unroll
    for (int r = 0; r < 16; ++r) {
      const int ql = (r & 3) + 8 * (r >> 2) + 4 * hi;
      out[(qrowb + ql) * 1024 + h * 64 + dt * 32 + l31] = po[dt][r] * ivLds[w][ql];
    }
}

extern "C" void kernel_launch(void* const* d_in, const int* in_sizes, int n_in,
                              void* d_out, int out_size, void* d_ws, size_t ws_size,
                              hipStream_t stream) {
  const float* inp1 = (const float*)d_in[0];
  const float* inp2 = (const float*)d_in[1];
  const float* Wq = (const float*)d_in[2];
  const float* bq = (const float*)d_in[3];
  const float* Wk = (const float*)d_in[4];
  const float* bk = (const float*)d_in[5];
  const float* Wv = (const float*)d_in[6];
  const float* bv = (const float*)d_in[7];
  const int* rs = (const int*)d_in[8];
  float* out = (float*)d_out;

  const float CEXP = 0.18033688011112042f;  // (1/8)*log2(e), folded into Wq/bq

  unsigned short* X1  = (unsigned short*)d_ws;              // [8192][1024] bf16
  unsigned short* X2  = X1 + (size_t)MROWS * 1024;
  unsigned short* Wqb = X2 + (size_t)MROWS * 1024;          // [1024][1024] bf16
  unsigned short* Wkb = Wqb + (size_t)1024 * 1024;
  unsigned short* Wvb = Wkb + (size_t)1024 * 1024;
  unsigned short* Qb  = Wvb + (size_t)1024 * 1024;          // [8192][1024] bf16
  unsigned short* Kb  = Qb + (size_t)MROWS * 1024;
  unsigned short* Vb  = Kb + (size_t)MROWS * 1024;

  // one flat convert launch: 2*N4I + 3*N4W float4 elems = 4,980,736 / 256 = 19456 blocks
  cvt_all_kernel<<<dim3((2 * N4I + 3 * N4W) / 256), 256, 0, stream>>>(
      inp1, X1, inp2, X2, Wq, Wqb, Wk, Wkb, Wv, Wvb, CEXP);

  gemm3_kernel<<<dim3(64, 8, 3), 256, 0, stream>>>(X1, X2, Wqb, Wkb, Wvb,
                                                   bq, bk, bv, Qb, Kb, Vb, CEXP);

  attn_kernel<<<dim3(512), 512, 0, stream>>>(Qb, Kb, Vb, out, rs);
}

// Round 15
// 147.104 us; speedup vs baseline: 1.0062x; 1.0062x over previous
//
#include <hip/hip_runtime.h>
#include <hip/hip_bf16.h>

// Problem constants
#define HEADS   16
#define HD      64
#define DMODEL  1024
#define LQ      2048
#define LK      2048
#define BATCH   4
#define MROWS   8192  // BATCH*LQ

typedef __attribute__((ext_vector_type(8))) short short8;   // 8 bf16 = 4 VGPR
typedef __attribute__((ext_vector_type(4))) float f32x4;    // MFMA 16x16 acc
typedef __attribute__((ext_vector_type(16))) float f32x16;  // MFMA 32x32 acc
typedef __attribute__((ext_vector_type(2))) unsigned int uint2v;
typedef __attribute__((ext_vector_type(2))) short bf16x2;

union V4u { unsigned u[4]; short8 s8; };

static __device__ __forceinline__ unsigned short f2bf(float f) {
  unsigned u = __builtin_bit_cast(unsigned, f);
  u = (u + 0x7FFFu + ((u >> 16) & 1u)) >> 16;  // RNE
  return (unsigned short)u;
}

static __device__ __forceinline__ unsigned cvtpk(float lo, float hi) {
  unsigned w;
  asm("v_cvt_pk_bf16_f32 %0, %1, %2" : "=v"(w) : "v"(lo), "v"(hi));
  return w;  // {lo16: bf16(lo), hi16: bf16(hi)}
}

// v_permlane32_swap_b32 vdst, vsrc: swaps vdst's UPPER 32 lanes with vsrc's
// LOWER 32 lanes (verified round 4).
static __device__ __forceinline__ void permswap(unsigned &a, unsigned &b) {
  asm volatile("v_permlane32_swap_b32 %0, %1" : "+v"(a), "+v"(b));
}

static __device__ __forceinline__ void gload_lds16(const void* g, void* l) {
  __builtin_amdgcn_global_load_lds(
      (const __attribute__((address_space(1))) unsigned int*)g,
      (__attribute__((address_space(3))) unsigned int*)l, 16, 0, 0);
}

static __device__ __forceinline__ unsigned lds_addr(const void* p) {
  return (unsigned)(size_t)(const __attribute__((address_space(3))) void*)p;
}

static __device__ __forceinline__ void ds_read128o(unsigned addr, int imm, V4u &d) {
  asm volatile("ds_read_b128 %0, %1 offset:%c2" : "=v"(d.s8) : "v"(addr), "i"(imm));
}

static __device__ __forceinline__ void ds_read_tro(unsigned addr, int imm, uint2v &d) {
  asm volatile("ds_read_b64_tr_b16 %0, %1 offset:%c2" : "=v"(d) : "v"(addr), "i"(imm));
}

// s2 += dot2(w, w), z += dot2(w, {1,1}) using bf16 dot if available.
#if __has_builtin(__builtin_amdgcn_fdot2_f32_bf16)
#define HAVE_BF16_DOT2 1
static __device__ __forceinline__ float dot2_sq(unsigned w, float acc) {
  bf16x2 v = __builtin_bit_cast(bf16x2, w);
  return __builtin_amdgcn_fdot2_f32_bf16(v, v, acc, false);
}
static __device__ __forceinline__ float dot2_sum(unsigned w, float acc) {
  bf16x2 ones = __builtin_bit_cast(bf16x2, 0x3F803F80u);  // {1.0bf, 1.0bf}
  bf16x2 v = __builtin_bit_cast(bf16x2, w);
  return __builtin_amdgcn_fdot2_f32_bf16(v, ones, acc, false);
}
#else
#define HAVE_BF16_DOT2 0
#endif

// ---------------- fp32 -> bf16 convert, single flat launch ----------------
// Flat float4-range: [0,N4I): inp1, [N4I,2*N4I): inp2, then Wq (scaled), Wk, Wv.
#define N4I 2097152   // 8192*1024/4
#define N4W 262144    // 1024*1024/4
__global__ void cvt_all_kernel(const float* __restrict__ i1, unsigned short* __restrict__ o1,
                               const float* __restrict__ i2, unsigned short* __restrict__ o2,
                               const float* __restrict__ wq, unsigned short* __restrict__ oq,
                               const float* __restrict__ wk, unsigned short* __restrict__ ok,
                               const float* __restrict__ wv, unsigned short* __restrict__ ov,
                               float scaleq) {
  int i = blockIdx.x * blockDim.x + threadIdx.x;
  const float* s;
  unsigned short* d;
  int off;
  float sc = 1.0f;
  if (i < 2 * N4I) {
    if (i < N4I) { s = i1; d = o1; off = i; }
    else { s = i2; d = o2; off = i - N4I; }
  } else {
    int j = i - 2 * N4I;
    if (j < N4W) { s = wq; d = oq; off = j; sc = scaleq; }
    else if (j < 2 * N4W) { s = wk; d = ok; off = j - N4W; }
    else { s = wv; d = ov; off = j - 2 * N4W; }
  }
  float4 v = ((const float4*)s)[off];
  ushort4 o;
  o.x = f2bf(v.x * sc); o.y = f2bf(v.y * sc); o.z = f2bf(v.z * sc); o.w = f2bf(v.w * sc);
  ((ushort4*)d)[off] = o;
}

// ---------------- fused QKV GEMM: z selects (A,W,bias,C,bscale) ----------------
// BK=64 (r13 proven): 16 K-steps, 2 barriers each. 128x128 tile, 4 waves,
// 32 KB LDS -> 4 blocks/CU. 8-slot rows with XOR (sl ^ (r&7)) swizzle.
__global__ __launch_bounds__(256, 4) void gemm3_kernel(
    const unsigned short* __restrict__ X1,
    const unsigned short* __restrict__ X2,
    const unsigned short* __restrict__ Wqb,
    const unsigned short* __restrict__ Wkb,
    const unsigned short* __restrict__ Wvb,
    const float* __restrict__ bq,
    const float* __restrict__ bk,
    const float* __restrict__ bv,
    unsigned short* __restrict__ Qb,
    unsigned short* __restrict__ Kb,
    unsigned short* __restrict__ Vb,
    float cexp) {
  __shared__ __attribute__((aligned(16))) unsigned short As[128 * 64];
  __shared__ __attribute__((aligned(16))) unsigned short Bs[128 * 64];
  const int sel = blockIdx.z;
  const unsigned short* A = (sel == 0) ? X1 : X2;
  const unsigned short* W = (sel == 0) ? Wqb : (sel == 1) ? Wkb : Wvb;
  const float* bias = (sel == 0) ? bq : (sel == 1) ? bk : bv;
  unsigned short* C = (sel == 0) ? Qb : (sel == 1) ? Kb : Vb;
  const float bscale = (sel == 0) ? cexp : 1.0f;

  const int tid = threadIdx.x;
  const int l = tid & 63, w = tid >> 6;
  const int c = l & 15, g = l >> 4;
  const int wm = w >> 1, wn = w & 1;
  const int m0 = blockIdx.x * 128, n0 = blockIdx.y * 128;

  f32x4 acc[4][4];
#pragma unroll
  for (int i = 0; i < 4; ++i)
#pragma unroll
    for (int j = 0; j < 4; ++j) acc[i][j] = (f32x4){0.f, 0.f, 0.f, 0.f};

  for (int k0 = 0; k0 < 1024; k0 += 64) {
#pragma unroll
    for (int is = 0; is < 4; ++is) {
      int lin = is * 256 + tid;
      int r = lin >> 3, sl = lin & 7;
      int gofs = (sl ^ (r & 7)) * 8;
      gload_lds16(A + (size_t)(m0 + r) * 1024 + k0 + gofs,
                  &As[(is * 256 + (tid & ~63)) * 8]);
      gload_lds16(W + (size_t)(n0 + r) * 1024 + k0 + gofs,
                  &Bs[(is * 256 + (tid & ~63)) * 8]);
    }
    __syncthreads();
#pragma unroll
    for (int kk = 0; kk < 2; ++kk) {
      short8 af[4], bfr[4];
#pragma unroll
      for (int mt = 0; mt < 4; ++mt) {
        int row = wm * 64 + mt * 16 + c;
        int ch = kk * 4 + g;
        af[mt] = *(const short8*)((const char*)As + row * 128 + ((ch ^ (row & 7)) << 4));
      }
#pragma unroll
      for (int nt = 0; nt < 4; ++nt) {
        int row = wn * 64 + nt * 16 + c;
        int ch = kk * 4 + g;
        bfr[nt] = *(const short8*)((const char*)Bs + row * 128 + ((ch ^ (row & 7)) << 4));
      }
      __builtin_amdgcn_s_setprio(1);
#pragma unroll
      for (int mt = 0; mt < 4; ++mt)
#pragma unroll
        for (int nt = 0; nt < 4; ++nt)
          acc[mt][nt] = __builtin_amdgcn_mfma_f32_16x16x32_bf16(af[mt], bfr[nt], acc[mt][nt], 0, 0, 0);
      __builtin_amdgcn_s_setprio(0);
    }
    __syncthreads();
  }
  float bv4[4];
#pragma unroll
  for (int nt = 0; nt < 4; ++nt) bv4[nt] = bias[n0 + wn * 64 + nt * 16 + c] * bscale;
#pragma unroll
  for (int mt = 0; mt < 4; ++mt)
#pragma unroll
    for (int nt = 0; nt < 4; ++nt)
#pragma unroll
      for (int r = 0; r < 4; ++r) {
        int m = m0 + wm * 64 + mt * 16 + g * 4 + r;
        int n = n0 + wn * 64 + nt * 16 + c;
        C[(size_t)m * 1024 + n] = f2bf(acc[mt][nt][r] + bv4[nt]);
      }
}

// ---------------- fused attention, 8-wave 32x32 swapped-QK^T ----------------
// EXACT round-9/13 kernel (best measured: 77.1 us) — frozen. KVBLK=64.
__global__ __launch_bounds__(512) void attn_kernel(
    const unsigned short* __restrict__ Q,
    const unsigned short* __restrict__ K,
    const unsigned short* __restrict__ V,
    float* __restrict__ out,
    const int* __restrict__ rescale_flag) {
  __shared__ __attribute__((aligned(16))) unsigned short Kbuf[2][64 * 64];
  __shared__ __attribute__((aligned(16))) unsigned short Vbuf[2][64 * 64];
  __shared__ float ivLds[8][32];

  const int tid = threadIdx.x;
  const int lane = tid & 63, w = tid >> 6;
  const int l31 = lane & 31, hi = lane >> 5;

  // XCD-locality remap: all 8 q-tiles of one (b,h) on one XCD (gid%8 = xcd).
  const int gid = blockIdx.x;
  const int xcd = gid & 7;
  const int o = gid >> 3;
  const int bh = xcd * 8 + (o >> 3);
  const int qb = o & 7;
  const int bb = bh >> 4, h = bh & 15;
  const size_t qrowb = (size_t)bb * LQ + qb * 256 + w * 32;

  const int rs = *rescale_flag;

  // Q fragments (B-operand of swapped QK^T): lane holds Q[q=l31][d=ks*16+hi*8+j]
  short8 qf[4];
#pragma unroll
  for (int ks = 0; ks < 4; ++ks)
    qf[ks] = *(const short8*)(Q + (qrowb + l31) * 1024 + h * 64 + ks * 16 + hi * 8);

  // Staging source offsets (per-lane, elems within the (b,h) K/V plane).
  const size_t kvbase = (size_t)bb * LK * 1024 + (size_t)h * 64;
  const int k_kv = w * 8 + (lane >> 3);
  const int k_sl = (lane & 7) ^ (lane >> 3);
  const unsigned short* ksrc0 = K + kvbase + (size_t)k_kv * 1024 + k_sl * 8;
  const int v_kv = (w & 3) * 16 + ((lane >> 4) & 1) * 8 + ((lane >> 5) & 1) * 4 + ((lane >> 1) & 3);
  const int v_d  = (w >> 2) * 32 + ((lane >> 3) & 1) * 16 + (lane & 1) * 8;
  const unsigned short* vsrc0 = V + kvbase + (size_t)v_kv * 1024 + v_d;

  // Per-lane K LDS read offsets (byte), constant across tiles/subtiles.
  unsigned koff[4];
#pragma unroll
  for (int ks = 0; ks < 4; ++ks)
    koff[ks] = (unsigned)(l31 * 128 + ((((ks << 1) | hi) ^ (l31 & 7)) << 4));
  const unsigned kbase0 = lds_addr(&Kbuf[0][0]);
  const unsigned vbase0 = lds_addr(&Vbuf[0][0]);

  f32x16 po[2];
  po[0] = {}; po[1] = {};
  float za0 = 0.f, za1 = 0.f, s20 = 0.f, s21 = 0.f;

  gload_lds16(ksrc0, &Kbuf[0][w * 512]);
  gload_lds16(vsrc0, &Vbuf[0][w * 512]);
  __syncthreads();

  int cur = 0;
  for (int t = 0; t < LK / 64; ++t) {
    if (t < LK / 64 - 1) {
      gload_lds16(ksrc0 + (size_t)(t + 1) * 65536, &Kbuf[cur ^ 1][w * 512]);
      gload_lds16(vsrc0 + (size_t)(t + 1) * 65536, &Vbuf[cur ^ 1][w * 512]);
    }
    unsigned kaddr[4];
#pragma unroll
    for (int ks = 0; ks < 4; ++ks) kaddr[ks] = kbase0 + (unsigned)(cur * 8192) + koff[ks];
    const unsigned vtr = vbase0 + (unsigned)(cur * 8192) + (unsigned)(lane * 8);

#pragma unroll
    for (int s = 0; s < 2; ++s) {
      // ---- issue ALL LDS reads for this subtile (4 K-frags + 8 V tr-reads)
      V4u kfr[4];
#pragma unroll
      for (int ks = 0; ks < 4; ++ks) ds_read128o(kaddr[ks], s * 4096, kfr[ks]);
      uint2v ta0, ta1, ta2, ta3, tb0, tb1, tb2, tb3;
      ds_read_tro(vtr, (2 * s) * 1024, ta0);
      ds_read_tro(vtr, (2 * s) * 1024 + 512, ta1);
      ds_read_tro(vtr, (2 * s) * 1024 + 4096, ta2);
      ds_read_tro(vtr, (2 * s) * 1024 + 4608, ta3);
      ds_read_tro(vtr, (2 * s + 1) * 1024, tb0);
      ds_read_tro(vtr, (2 * s + 1) * 1024 + 512, tb1);
      ds_read_tro(vtr, (2 * s + 1) * 1024 + 4096, tb2);
      ds_read_tro(vtr, (2 * s + 1) * 1024 + 4608, tb3);
      asm volatile("s_waitcnt lgkmcnt(8)" ::: "memory");  // K-frags ready
      __builtin_amdgcn_sched_barrier(0);
      // ---- QK^T (swapped): ps = S^T[kv=crow(r,hi)+32s][q=l31]
      f32x16 ps = {};
      __builtin_amdgcn_s_setprio(1);
      ps = __builtin_amdgcn_mfma_f32_32x32x16_bf16(kfr[0].s8, qf[0], ps, 0, 0, 0);
      ps = __builtin_amdgcn_mfma_f32_32x32x16_bf16(kfr[1].s8, qf[1], ps, 0, 0, 0);
      ps = __builtin_amdgcn_mfma_f32_32x32x16_bf16(kfr[2].s8, qf[2], ps, 0, 0, 0);
      ps = __builtin_amdgcn_mfma_f32_32x32x16_bf16(kfr[3].s8, qf[3], ps, 0, 0, 0);
      __builtin_amdgcn_s_setprio(0);
      // ---- softmax piece: lane-local exp
      float p[16];
#pragma unroll
      for (int r = 0; r < 16; ++r) p[r] = __builtin_amdgcn_exp2f(ps[r]);
      // ---- pack P to bf16 words (cvt_pk); wlo[b]={kv 8b+4hi, +1}, whi[b]={+2,+3}
      unsigned wlo[4], whi[4];
#pragma unroll
      for (int b = 0; b < 4; ++b) {
        wlo[b] = cvtpk(p[4 * b + 0], p[4 * b + 1]);
        whi[b] = cvtpk(p[4 * b + 2], p[4 * b + 3]);
      }
      // ---- accumulate z or s2 from packed words (off the PV critical path)
#if HAVE_BF16_DOT2
      if (rs) {
#pragma unroll
        for (int b = 0; b < 4; ++b) {
          s20 = dot2_sq(wlo[b], s20);
          s21 = dot2_sq(whi[b], s21);
        }
      } else {
#pragma unroll
        for (int b = 0; b < 4; ++b) {
          za0 = dot2_sum(wlo[b], za0);
          za1 = dot2_sum(whi[b], za1);
        }
      }
#else
      if (rs) {
#pragma unroll
        for (int r = 0; r < 8; ++r) {
          s20 = fmaf(p[2 * r], p[2 * r], s20);
          s21 = fmaf(p[2 * r + 1], p[2 * r + 1], s21);
        }
      } else {
#pragma unroll
        for (int r = 0; r < 8; ++r) {
          za0 += p[2 * r];
          za1 += p[2 * r + 1];
        }
      }
#endif
      // ---- PV ks=0 (kv4 = 2s): first 4 tr-reads ready at lgkmcnt(4)
      {
        unsigned a0 = wlo[0], b0 = wlo[1], a1 = whi[0], b1 = whi[1];
        permswap(a0, b0);
        permswap(a1, b1);
        V4u pau; pau.u[0] = a0; pau.u[1] = a1; pau.u[2] = b0; pau.u[3] = b1;
        asm volatile("s_waitcnt lgkmcnt(4)" ::: "memory");
        __builtin_amdgcn_sched_barrier(0);
        V4u v0u, v1u;
        v0u.u[0] = ta0[0]; v0u.u[1] = ta0[1]; v0u.u[2] = ta1[0]; v0u.u[3] = ta1[1];
        v1u.u[0] = ta2[0]; v1u.u[1] = ta2[1]; v1u.u[2] = ta3[0]; v1u.u[3] = ta3[1];
        __builtin_amdgcn_s_setprio(1);
        po[0] = __builtin_amdgcn_mfma_f32_32x32x16_bf16(pau.s8, v0u.s8, po[0], 0, 0, 0);
        po[1] = __builtin_amdgcn_mfma_f32_32x32x16_bf16(pau.s8, v1u.s8, po[1], 0, 0, 0);
        __builtin_amdgcn_s_setprio(0);
      }
      // ---- PV ks=1 (kv4 = 2s+1): remaining tr-reads at lgkmcnt(0)
      {
        unsigned a0 = wlo[2], b0 = wlo[3], a1 = whi[2], b1 = whi[3];
        permswap(a0, b0);
        permswap(a1, b1);
        V4u pau; pau.u[0] = a0; pau.u[1] = a1; pau.u[2] = b0; pau.u[3] = b1;
        asm volatile("s_waitcnt lgkmcnt(0)" ::: "memory");
        __builtin_amdgcn_sched_barrier(0);
        V4u v0u, v1u;
        v0u.u[0] = tb0[0]; v0u.u[1] = tb0[1]; v0u.u[2] = tb1[0]; v0u.u[3] = tb1[1];
        v1u.u[0] = tb2[0]; v1u.u[1] = tb2[1]; v1u.u[2] = tb3[0]; v1u.u[3] = tb3[1];
        __builtin_amdgcn_s_setprio(1);
        po[0] = __builtin_amdgcn_mfma_f32_32x32x16_bf16(pau.s8, v0u.s8, po[0], 0, 0, 0);
        po[1] = __builtin_amdgcn_mfma_f32_32x32x16_bf16(pau.s8, v1u.s8, po[1], 0, 0, 0);
        __builtin_amdgcn_s_setprio(0);
      }
    }
    __syncthreads();
    cur ^= 1;
  }

  // ---- denominators: combine accumulators, then the two kv-halves
  float zacc = za0 + za1;
  float s2acc = s20 + s21;
  float z2 = zacc + __shfl_xor(zacc, 32, 64);
  float s22 = s2acc + __shfl_xor(s2acc, 32, 64);
  float iv = rs ? (1.0f / sqrtf(s22)) : (1.0f / z2);
  ivLds[w][l31] = iv;  // both halves write identical value

  // ---- store: O[q=qrowb+crow(r,hi)][d=h*64+dt*32+l31] * iv[q]
#pragma unroll
  for (int dt = 0; dt < 2; ++dt)
#pragma unroll
    for (int r = 0; r < 16; ++r) {
      const int ql = (r & 3) + 8 * (r >> 2) + 4 * hi;
      out[(qrowb + ql) * 1024 + h * 64 + dt * 32 + l31] = po[dt][r] * ivLds[w][ql];
    }
}

extern "C" void kernel_launch(void* const* d_in, const int* in_sizes, int n_in,
                              void* d_out, int out_size, void* d_ws, size_t ws_size,
                              hipStream_t stream) {
  const float* inp1 = (const float*)d_in[0];
  const float* inp2 = (const float*)d_in[1];
  const float* Wq = (const float*)d_in[2];
  const float* bq = (const float*)d_in[3];
  const float* Wk = (const float*)d_in[4];
  const float* bk = (const float*)d_in[5];
  const float* Wv = (const float*)d_in[6];
  const float* bv = (const float*)d_in[7];
  const int* rs = (const int*)d_in[8];
  float* out = (float*)d_out;

  const float CEXP = 0.18033688011112042f;  // (1/8)*log2(e), folded into Wq/bq

  unsigned short* X1  = (unsigned short*)d_ws;              // [8192][1024] bf16
  unsigned short* X2  = X1 + (size_t)MROWS * 1024;
  unsigned short* Wqb = X2 + (size_t)MROWS * 1024;          // [1024][1024] bf16
  unsigned short* Wkb = Wqb + (size_t)1024 * 1024;
  unsigned short* Wvb = Wkb + (size_t)1024 * 1024;
  unsigned short* Qb  = Wvb + (size_t)1024 * 1024;          // [8192][1024] bf16
  unsigned short* Kb  = Qb + (size_t)MROWS * 1024;
  unsigned short* Vb  = Kb + (size_t)MROWS * 1024;

  // one flat convert launch: 2*N4I + 3*N4W float4 elems = 4,980,736 / 256 = 19456 blocks
  cvt_all_kernel<<<dim3((2 * N4I + 3 * N4W) / 256), 256, 0, stream>>>(
      inp1, X1, inp2, X2, Wq, Wqb, Wk, Wkb, Wv, Wvb, CEXP);

  gemm3_kernel<<<dim3(64, 8, 3), 256, 0, stream>>>(X1, X2, Wqb, Wkb, Wvb,
                                                   bq, bk, bv, Qb, Kb, Vb, CEXP);

  attn_kernel<<<dim3(512), 512, 0, stream>>>(Qb, Kb, Vb, out, rs);
}